// Round 11
// baseline (274.977 us; speedup 1.0000x reference)
//
#include <hip/hip_runtime.h>

// GCN layer: segment_sum(x@W^T)[dst] == segment_sum(x)[dst] @ W^T (linearity).
// Round-11: 4 dispatches, zero global atomics, scan computed exactly once,
// node-sort in LDS inside the gather (128-node buckets, no over-read).
//   K1 convert_hist : x->bf16 (+zero row N); LDS hist over nb=ceil(N/128)
//                     buckets -> scanbuf[b*PB + bid]
//   K2 scan2d       : ONE block: in-place exclusive scan of each bucket row
//                     (PB entries) + parallel scan of bucket totals -> gbase
//   K3 scatter      : curs[b]=gbase[b]+scanbuf[b][bid]; LDS cursors;
//                     binned[p] = (src<<7)|(dst&127)
//   K4 sort_gather  : block per 128-node bucket; reads ITS 8KB segment only;
//                     LDS counting sort -> slds; branchless quad gather
//                     (4 bf16 dwordx4 row loads in flight, zero-row redirect,
//                     shfl_xor reduce, readlane @ W^T epilogue)
// Tier D fallback (tiny ws / huge N): atomic scatter + LDS linear.

#define DIM 64
#define BN 128            // nodes per bucket
#define BN_SHIFT 7
#define BN_MASK 127
#define NB_MAX 1024       // max buckets in LDS (hist/cursors)
#define PB 256            // hist/scatter blocks
#define CAP 3072          // LDS src capacity per gather block (avg ~2048)

__device__ __forceinline__ unsigned short f32_to_bf16_rne(float f) {
    unsigned u = __float_as_uint(f);
    unsigned r = u + 0x7FFFu + ((u >> 16) & 1u);
    return (unsigned short)(r >> 16);
}

// ---------------------------------------------------------------------------
// K1: convert x -> bf16 (incl. zero row N) + per-block LDS histogram.
__global__ __launch_bounds__(256) void convert_hist_kernel(
        const float* __restrict__ x, const int* __restrict__ ei,
        ushort4* __restrict__ xb4, int* __restrict__ scanbuf,
        int E, int N, int nb, int total4) {
    __shared__ int h[NB_MAX];
    const int t = threadIdx.x;
    const int bid = blockIdx.x;

    for (int b = t; b < nb; b += 256) h[b] = 0;
    __syncthreads();

    for (int i = bid * 256 + t; i < total4; i += PB * 256) {
        float4 v = ((const float4*)x)[i];
        ushort4 o;
        o.x = f32_to_bf16_rne(v.x); o.y = f32_to_bf16_rne(v.y);
        o.z = f32_to_bf16_rne(v.z); o.w = f32_to_bf16_rne(v.w);
        xb4[i] = o;
    }
    if (bid == 0 && t < 16) {                 // zero row N
        ushort4 z; z.x = 0; z.y = 0; z.z = 0; z.w = 0;
        xb4[(size_t)N * 16 + t] = z;
    }

    for (int e = bid * 256 + t; e < E; e += PB * 256)
        atomicAdd(&h[ei[E + e] >> BN_SHIFT], 1);
    __syncthreads();
    for (int b = t; b < nb; b += 256)
        scanbuf[b * PB + bid] = h[b];
}

// ---------------------------------------------------------------------------
// K2: single-block 2D scan. In-place exclusive scan of each bucket's PB-entry
// row; bucket totals -> parallel exclusive scan -> gbase[nb+1].
__global__ __launch_bounds__(256) void scan2d_kernel(
        int* __restrict__ buf, int* __restrict__ gbase, int nb, int E) {
    __shared__ int tot[NB_MAX];
    __shared__ int tmp[256];
    const int t = threadIdx.x;

    for (int row = t; row < nb; row += 256) {
        int4* r = (int4*)(buf + (size_t)row * PB);
        int run = 0;
        #pragma unroll 4
        for (int k = 0; k < PB / 4; ++k) {
            int4 v = r[k];
            int4 w;
            w.x = run; run += v.x;
            w.y = run; run += v.y;
            w.z = run; run += v.z;
            w.w = run; run += v.w;
            r[k] = w;
        }
        tot[row] = run;
    }
    for (int row = nb + t; row < NB_MAX; row += 256) tot[row] = 0;
    __syncthreads();

    // exclusive scan of 1024 totals (4 per thread)
    int c0 = tot[4 * t + 0], c1 = tot[4 * t + 1];
    int c2 = tot[4 * t + 2], c3 = tot[4 * t + 3];
    int s4 = c0 + c1 + c2 + c3;
    tmp[t] = s4;
    __syncthreads();
    #pragma unroll
    for (int d = 1; d < 256; d <<= 1) {
        int u = (t >= d) ? tmp[t - d] : 0;
        __syncthreads();
        tmp[t] += u;
        __syncthreads();
    }
    int excl = tmp[t] - s4;
    if (4 * t + 0 < nb) gbase[4 * t + 0] = excl;
    if (4 * t + 1 < nb) gbase[4 * t + 1] = excl + c0;
    if (4 * t + 2 < nb) gbase[4 * t + 2] = excl + c0 + c1;
    if (4 * t + 3 < nb) gbase[4 * t + 3] = excl + c0 + c1 + c2;
    if (t == 0) gbase[nb] = E;
}

// ---------------------------------------------------------------------------
// K3: scatter edges into bucket-grouped binned[] via LDS cursors.
__global__ __launch_bounds__(256) void scatter_kernel(
        const int* __restrict__ ei, const int* __restrict__ scanbuf,
        const int* __restrict__ gbase, int* __restrict__ binned, int E, int nb) {
    __shared__ int curs[NB_MAX];
    const int t = threadIdx.x;
    const int bid = blockIdx.x;

    for (int b = t; b < nb; b += 256)
        curs[b] = gbase[b] + scanbuf[b * PB + bid];
    __syncthreads();

    for (int e = bid * 256 + t; e < E; e += PB * 256) {
        int s = ei[e];
        int d = ei[E + e];
        int p = atomicAdd(&curs[d >> BN_SHIFT], 1);
        binned[p] = (s << BN_SHIFT) | (d & BN_MASK);
    }
}

// ---------------------------------------------------------------------------
// Gather helpers (proven r8/r10).
__device__ __forceinline__ void acc8(float (&a)[8], const uint4& v) {
    a[0] += __uint_as_float(v.x << 16); a[1] += __uint_as_float(v.x & 0xFFFF0000u);
    a[2] += __uint_as_float(v.y << 16); a[3] += __uint_as_float(v.y & 0xFFFF0000u);
    a[4] += __uint_as_float(v.z << 16); a[5] += __uint_as_float(v.z & 0xFFFF0000u);
    a[6] += __uint_as_float(v.w << 16); a[7] += __uint_as_float(v.w & 0xFFFF0000u);
}

__device__ __forceinline__ float epilogue64(const float (&a)[8],
                                            const float (&wv)[DIM], float bb) {
    float r0 = bb, r1 = 0.f, r2 = 0.f, r3 = 0.f;
    #pragma unroll
    for (int k = 0; k < DIM; k += 4) {
        r0 += __int_as_float(__builtin_amdgcn_readlane(
                  __float_as_int(a[(k + 0) & 7]), (k + 0) >> 3)) * wv[k + 0];
        r1 += __int_as_float(__builtin_amdgcn_readlane(
                  __float_as_int(a[(k + 1) & 7]), (k + 1) >> 3)) * wv[k + 1];
        r2 += __int_as_float(__builtin_amdgcn_readlane(
                  __float_as_int(a[(k + 2) & 7]), (k + 2) >> 3)) * wv[k + 2];
        r3 += __int_as_float(__builtin_amdgcn_readlane(
                  __float_as_int(a[(k + 3) & 7]), (k + 3) >> 3)) * wv[k + 3];
    }
    return (r0 + r1) + (r2 + r3);
}

// ---------------------------------------------------------------------------
// K4: block per 128-node bucket. LDS counting sort of its own segment, then
// branchless quad gather.
__global__ __launch_bounds__(256) void sort_gather_kernel(
        const unsigned short* __restrict__ xh, const int* __restrict__ binned,
        const int* __restrict__ gbase, int* __restrict__ gsrcs,
        const float* __restrict__ W, const float* __restrict__ bias,
        float* __restrict__ out, int N, int E) {
    __shared__ int cnt[BN];
    __shared__ int basel[BN + 1];
    __shared__ int tmp[BN];
    __shared__ int slds[CAP];

    const int t = threadIdx.x;
    const int g = blockIdx.x;
    const int lane = t & 63;
    const int wid = t >> 6;
    const int node0 = g << BN_SHIFT;

    // W row `lane` + bias (overlaps with sort)
    float wv[DIM];
    #pragma unroll
    for (int k4 = 0; k4 < DIM / 4; ++k4) {
        float4 tw = *(const float4*)(W + (size_t)lane * DIM + k4 * 4);
        wv[k4 * 4 + 0] = tw.x; wv[k4 * 4 + 1] = tw.y;
        wv[k4 * 4 + 2] = tw.z; wv[k4 * 4 + 3] = tw.w;
    }
    const float bb = bias[lane];

    const int seg0 = gbase[g];
    const int seg1 = gbase[g + 1];
    const int total = seg1 - seg0;

    if (t < BN) cnt[t] = 0;
    __syncthreads();

    // pass 1: count per-node
    for (int i = seg0 + t; i < seg1; i += 256)
        atomicAdd(&cnt[binned[i] & BN_MASK], 1);
    __syncthreads();

    // exclusive prefix over 128 counters
    int myv = (t < BN) ? cnt[t] : 0;
    if (t < BN) tmp[t] = myv;
    __syncthreads();
    #pragma unroll
    for (int d = 1; d < BN; d <<= 1) {
        int u = (t < BN && t >= d) ? tmp[t - d] : 0;
        __syncthreads();
        if (t < BN) tmp[t] += u;
        __syncthreads();
    }
    if (t < BN) basel[t] = tmp[t] - myv;
    if (t == BN - 1) basel[BN] = tmp[t];
    if (t < BN) cnt[t] = tmp[t] - myv;        // cursors
    __syncthreads();

    const bool fits = (total <= CAP);
    // pass 2: scatter srcs (LDS if fits, else global scratch)
    if (fits) {
        for (int i = seg0 + t; i < seg1; i += 256) {
            int v = binned[i];                // L2-hot re-read (8KB window)
            int p = atomicAdd(&cnt[v & BN_MASK], 1);
            slds[p] = v >> BN_SHIFT;
        }
    } else {
        for (int i = seg0 + t; i < seg1; i += 256) {
            int v = binned[i];
            int p = atomicAdd(&cnt[v & BN_MASK], 1);
            gsrcs[seg0 + p] = v >> BN_SHIFT;
        }
    }
    __syncthreads();

    // branchless quad gather
    const int sub8 = lane >> 3;
    const int fb   = (lane & 7) << 3;
    const int zrow = N;
    const int slast = E + 48;
    for (int q = wid; q < (BN >> 2); q += 4) {
        const int nl = q << 2;
        int b0 = basel[nl + 0], e0 = basel[nl + 1];
        int b1 = basel[nl + 1], e1 = basel[nl + 2];
        int b2 = basel[nl + 2], e2 = basel[nl + 3];
        int b3 = basel[nl + 3], e3 = basel[nl + 4];
        int c0 = (e0 - b0 + 7) >> 3, c1 = (e1 - b1 + 7) >> 3;
        int c2 = (e2 - b2 + 7) >> 3, c3 = (e3 - b3 + 7) >> 3;
        int cmax = max(max(c0, c1), max(c2, c3));
        cmax = __builtin_amdgcn_readfirstlane(cmax);

        float A0[8] = {0.f,0.f,0.f,0.f,0.f,0.f,0.f,0.f};
        float A1[8] = {0.f,0.f,0.f,0.f,0.f,0.f,0.f,0.f};
        float A2[8] = {0.f,0.f,0.f,0.f,0.f,0.f,0.f,0.f};
        float A3[8] = {0.f,0.f,0.f,0.f,0.f,0.f,0.f,0.f};

        if (fits) {
            for (int c = 0; c < cmax; ++c) {
                const int o = (c << 3) + sub8;
                int i0 = b0 + o, i1 = b1 + o, i2 = b2 + o, i3 = b3 + o;
                int s0 = slds[min(i0, CAP - 1)];
                int s1 = slds[min(i1, CAP - 1)];
                int s2 = slds[min(i2, CAP - 1)];
                int s3 = slds[min(i3, CAP - 1)];
                s0 = (i0 < e0) ? s0 : zrow;
                s1 = (i1 < e1) ? s1 : zrow;
                s2 = (i2 < e2) ? s2 : zrow;
                s3 = (i3 < e3) ? s3 : zrow;
                uint4 v0 = *(const uint4*)(xh + (size_t)s0 * DIM + fb);
                uint4 v1 = *(const uint4*)(xh + (size_t)s1 * DIM + fb);
                uint4 v2 = *(const uint4*)(xh + (size_t)s2 * DIM + fb);
                uint4 v3 = *(const uint4*)(xh + (size_t)s3 * DIM + fb);
                acc8(A0, v0); acc8(A1, v1); acc8(A2, v2); acc8(A3, v3);
            }
        } else {
            for (int c = 0; c < cmax; ++c) {
                const int o = (c << 3) + sub8;
                int i0 = b0 + o, i1 = b1 + o, i2 = b2 + o, i3 = b3 + o;
                int s0 = gsrcs[min(seg0 + i0, slast)];
                int s1 = gsrcs[min(seg0 + i1, slast)];
                int s2 = gsrcs[min(seg0 + i2, slast)];
                int s3 = gsrcs[min(seg0 + i3, slast)];
                s0 = (i0 < e0) ? s0 : zrow;
                s1 = (i1 < e1) ? s1 : zrow;
                s2 = (i2 < e2) ? s2 : zrow;
                s3 = (i3 < e3) ? s3 : zrow;
                uint4 v0 = *(const uint4*)(xh + (size_t)s0 * DIM + fb);
                uint4 v1 = *(const uint4*)(xh + (size_t)s1 * DIM + fb);
                uint4 v2 = *(const uint4*)(xh + (size_t)s2 * DIM + fb);
                uint4 v3 = *(const uint4*)(xh + (size_t)s3 * DIM + fb);
                acc8(A0, v0); acc8(A1, v1); acc8(A2, v2); acc8(A3, v3);
            }
        }

        #pragma unroll
        for (int d = 8; d <= 32; d <<= 1) {
            #pragma unroll
            for (int j = 0; j < 8; ++j) {
                A0[j] += __shfl_xor(A0[j], d, 64);
                A1[j] += __shfl_xor(A1[j], d, 64);
                A2[j] += __shfl_xor(A2[j], d, 64);
                A3[j] += __shfl_xor(A3[j], d, 64);
            }
        }

        const int n0 = node0 + nl;
        if (n0 + 0 < N) out[(size_t)(n0 + 0) * DIM + lane] = epilogue64(A0, wv, bb);
        if (n0 + 1 < N) out[(size_t)(n0 + 1) * DIM + lane] = epilogue64(A1, wv, bb);
        if (n0 + 2 < N) out[(size_t)(n0 + 2) * DIM + lane] = epilogue64(A2, wv, bb);
        if (n0 + 3 < N) out[(size_t)(n0 + 3) * DIM + lane] = epilogue64(A3, wv, bb);
    }
}

// ------------------- tier D: atomic scatter fallback -----------------------
__global__ void gcn_scatter_kernel(const float* __restrict__ x,
                                   const int* __restrict__ edge_index,
                                   float* __restrict__ out, int n_edges) {
    int gid = blockIdx.x * blockDim.x + threadIdx.x;
    int e = gid >> 4;
    if (e >= n_edges) return;
    int j = (gid & 15) << 2;
    int src = edge_index[e];
    int dst = edge_index[n_edges + e];
    const float4 v = *(const float4*)(x + (size_t)src * DIM + j);
    float* o = out + (size_t)dst * DIM + j;
    atomicAdd(o + 0, v.x); atomicAdd(o + 1, v.y);
    atomicAdd(o + 2, v.z); atomicAdd(o + 3, v.w);
}

__global__ void gcn_linear_inplace_kernel(float* __restrict__ out,
                                          const float* __restrict__ W,
                                          const float* __restrict__ bias,
                                          int n_nodes) {
    __shared__ float Wt[DIM * DIM];
    __shared__ float rows[4][DIM];
    int tid = threadIdx.x;
    int col = tid & 63;
    int r = tid >> 6;
    for (int i = tid; i < DIM * DIM; i += 256) {
        int c = i >> 6, k = i & 63;
        Wt[k * DIM + c] = W[i];
    }
    int row = blockIdx.x * 4 + r;
    if (row < n_nodes) rows[r][col] = out[(size_t)row * DIM + col];
    __syncthreads();
    if (row < n_nodes) {
        float a = 0.f;
        #pragma unroll
        for (int k = 0; k < DIM; ++k) a += rows[r][k] * Wt[k * DIM + col];
        out[(size_t)row * DIM + col] = a + bias[col];
    }
}

// ===========================================================================
extern "C" void kernel_launch(void* const* d_in, const int* in_sizes, int n_in,
                              void* d_out, int out_size, void* d_ws, size_t ws_size,
                              hipStream_t stream) {
    const float* x          = (const float*)d_in[0];   // [N, 64]
    const float* W          = (const float*)d_in[1];   // [64, 64]
    const float* bias       = (const float*)d_in[2];   // [64]
    const int*   edge_index = (const int*)d_in[3];     // [2, E] (int32)

    const int E = in_sizes[3] / 2;
    const int N = in_sizes[0] / DIM;
    float* out = (float*)d_out;

    const int nb = (N + BN - 1) >> BN_SHIFT;
    const int block = 256;

    auto align256 = [](size_t v) { return (v + 255) & ~(size_t)255; };
    const size_t xb_b   = align256(((size_t)N + 1) * DIM * 2);   // +1 zero row
    const size_t bin_b  = align256((size_t)E * 4);
    const size_t scan_b = align256((size_t)nb * PB * 4);
    const size_t gb_b   = align256(((size_t)nb + 1) * 4);
    const size_t srcs_b = align256(((size_t)E + 64) * 4);        // overflow path
    const size_t needA = xb_b + bin_b + scan_b + gb_b + srcs_b;

    // src must fit in 25 bits for the (src<<7)|dstlo packing
    if (nb <= NB_MAX && N < (1 << 24) && ws_size >= needA) {
        char* p = (char*)d_ws;
        ushort4* xb4 = (ushort4*)p;          p += xb_b;
        int* binned  = (int*)p;              p += bin_b;
        int* scanbuf = (int*)p;              p += scan_b;
        int* gbase   = (int*)p;              p += gb_b;
        int* gsrcs   = (int*)p;

        const int total4 = N * DIM / 4;

        convert_hist_kernel<<<PB, block, 0, stream>>>(
            x, edge_index, xb4, scanbuf, E, N, nb, total4);
        scan2d_kernel<<<1, block, 0, stream>>>(scanbuf, gbase, nb, E);
        scatter_kernel<<<PB, block, 0, stream>>>(
            edge_index, scanbuf, gbase, binned, E, nb);
        sort_gather_kernel<<<nb, block, 0, stream>>>(
            (const unsigned short*)xb4, binned, gbase, gsrcs, W, bias, out, N, E);
    } else {
        hipMemsetAsync(d_out, 0, (size_t)out_size * sizeof(float), stream);
        long long total = (long long)E * 16;
        int grid = (int)((total + block - 1) / block);
        gcn_scatter_kernel<<<grid, block, 0, stream>>>(x, edge_index, out, E);
        int lgrid = (N + 3) / 4;
        gcn_linear_inplace_kernel<<<lgrid, 256, 0, stream>>>(out, W, bias, N);
    }
}

// Round 12
// 210.803 us; speedup vs baseline: 1.3044x; 1.3044x over previous
//
#include <hip/hip_runtime.h>

// GCN layer: segment_sum(x@W^T)[dst] == segment_sum(x)[dst] @ W^T (linearity).
// Round-12: 5 dispatches, zero global atomics, all phases parallel.
//   K1 convert_hist : 1024 thr/block (16 waves/CU); x->bf16 (+zero row N);
//                     LDS hist over nb=ceil(N/128) buckets -> scanbuf[b*PB+bid]
//   K2a rowscan     : ONE WAVE PER ROW (782 waves): in-place exclusive scan
//                     of each 256-entry row (int4 + shfl), rowtot[b]
//   K2b basescan    : 1 small block: exclusive scan of rowtot -> gbase[nb+1]
//   K3 scatter      : 1024 thr/block; curs[b]=gbase[b]+scanbuf[b][bid];
//                     LDS cursors; binned[p] = (src<<7)|(dst&127)
//   K4 sort_gather  : (r11, proven 86us) block per 128-node bucket; LDS
//                     counting sort of its own 8KB segment; branchless quad
//                     gather (bf16 dwordx4, zero-row redirect, shfl_xor
//                     reduce, readlane @ W^T epilogue)
// Tier D fallback (tiny ws / huge N): atomic scatter + LDS linear.

#define DIM 64
#define BN 128            // nodes per bucket
#define BN_SHIFT 7
#define BN_MASK 127
#define NB_MAX 1024       // max buckets in LDS
#define PB 256            // hist/scatter blocks (matrix width)
#define CAP 3072          // LDS src capacity per gather block (avg ~2048)

__device__ __forceinline__ unsigned short f32_to_bf16_rne(float f) {
    unsigned u = __float_as_uint(f);
    unsigned r = u + 0x7FFFu + ((u >> 16) & 1u);
    return (unsigned short)(r >> 16);
}

// ---------------------------------------------------------------------------
// K1: convert x -> bf16 (incl. zero row N) + per-block LDS histogram.
// 1024 threads/block, PB blocks -> 16 waves/CU.
__global__ __launch_bounds__(1024) void convert_hist_kernel(
        const float* __restrict__ x, const int* __restrict__ ei,
        ushort4* __restrict__ xb4, int* __restrict__ scanbuf,
        int E, int N, int nb, int total4) {
    __shared__ int h[NB_MAX];
    const int t = threadIdx.x;
    const int bid = blockIdx.x;

    for (int b = t; b < nb; b += 1024) h[b] = 0;
    __syncthreads();

    for (int i = bid * 1024 + t; i < total4; i += PB * 1024) {
        float4 v = ((const float4*)x)[i];
        ushort4 o;
        o.x = f32_to_bf16_rne(v.x); o.y = f32_to_bf16_rne(v.y);
        o.z = f32_to_bf16_rne(v.z); o.w = f32_to_bf16_rne(v.w);
        xb4[i] = o;
    }
    if (bid == 0 && t < 16) {                 // zero row N
        ushort4 z; z.x = 0; z.y = 0; z.z = 0; z.w = 0;
        xb4[(size_t)N * 16 + t] = z;
    }

    for (int e = bid * 1024 + t; e < E; e += PB * 1024)
        atomicAdd(&h[ei[E + e] >> BN_SHIFT], 1);
    __syncthreads();
    for (int b = t; b < nb; b += 1024)
        scanbuf[b * PB + bid] = h[b];
}

// ---------------------------------------------------------------------------
// K2a: one wave per row; in-place exclusive scan of 256-entry row + rowtot.
__global__ __launch_bounds__(256) void rowscan_kernel(
        int* __restrict__ buf, int* __restrict__ rowtot, int nb) {
    const int lane = threadIdx.x & 63;
    const int row = blockIdx.x * 4 + (threadIdx.x >> 6);
    if (row >= nb) return;

    int4* r = (int4*)(buf + (size_t)row * PB);
    int4 v = r[lane];
    // lane-local inclusive of 4
    int s0 = v.x, s1 = s0 + v.y, s2 = s1 + v.z, s3 = s2 + v.w;
    // wave-exclusive scan of lane sums
    int ls = s3;
    int incl = ls;
    #pragma unroll
    for (int d = 1; d < 64; d <<= 1) {
        int u = __shfl_up(incl, d, 64);
        if (lane >= d) incl += u;
    }
    int excl = incl - ls;
    int4 w;
    w.x = excl;
    w.y = excl + s0;
    w.z = excl + s1;
    w.w = excl + s2;
    r[lane] = w;
    if (lane == 63) rowtot[row] = incl;       // row total
}

// ---------------------------------------------------------------------------
// K2b: single small block scans nb rowtots -> gbase[nb+1].
__global__ __launch_bounds__(256) void basescan_kernel(
        const int* __restrict__ rowtot, int* __restrict__ gbase, int nb, int E) {
    __shared__ int tot[NB_MAX];
    __shared__ int tmp[256];
    const int t = threadIdx.x;
    for (int j = t; j < NB_MAX; j += 256) tot[j] = (j < nb) ? rowtot[j] : 0;
    __syncthreads();
    int c0 = tot[4 * t + 0], c1 = tot[4 * t + 1];
    int c2 = tot[4 * t + 2], c3 = tot[4 * t + 3];
    int s4 = c0 + c1 + c2 + c3;
    tmp[t] = s4;
    __syncthreads();
    #pragma unroll
    for (int d = 1; d < 256; d <<= 1) {
        int u = (t >= d) ? tmp[t - d] : 0;
        __syncthreads();
        tmp[t] += u;
        __syncthreads();
    }
    int excl = tmp[t] - s4;
    if (4 * t + 0 < nb) gbase[4 * t + 0] = excl;
    if (4 * t + 1 < nb) gbase[4 * t + 1] = excl + c0;
    if (4 * t + 2 < nb) gbase[4 * t + 2] = excl + c0 + c1;
    if (4 * t + 3 < nb) gbase[4 * t + 3] = excl + c0 + c1 + c2;
    if (t == 0) gbase[nb] = E;
}

// ---------------------------------------------------------------------------
// K3: scatter edges into bucket-grouped binned[] via LDS cursors (1024 thr).
__global__ __launch_bounds__(1024) void scatter_kernel(
        const int* __restrict__ ei, const int* __restrict__ scanbuf,
        const int* __restrict__ gbase, int* __restrict__ binned, int E, int nb) {
    __shared__ int curs[NB_MAX];
    const int t = threadIdx.x;
    const int bid = blockIdx.x;

    for (int b = t; b < nb; b += 1024)
        curs[b] = gbase[b] + scanbuf[b * PB + bid];
    __syncthreads();

    for (int e = bid * 1024 + t; e < E; e += PB * 1024) {
        int s = ei[e];
        int d = ei[E + e];
        int p = atomicAdd(&curs[d >> BN_SHIFT], 1);
        binned[p] = (s << BN_SHIFT) | (d & BN_MASK);
    }
}

// ---------------------------------------------------------------------------
// Gather helpers (proven r8/r10/r11).
__device__ __forceinline__ void acc8(float (&a)[8], const uint4& v) {
    a[0] += __uint_as_float(v.x << 16); a[1] += __uint_as_float(v.x & 0xFFFF0000u);
    a[2] += __uint_as_float(v.y << 16); a[3] += __uint_as_float(v.y & 0xFFFF0000u);
    a[4] += __uint_as_float(v.z << 16); a[5] += __uint_as_float(v.z & 0xFFFF0000u);
    a[6] += __uint_as_float(v.w << 16); a[7] += __uint_as_float(v.w & 0xFFFF0000u);
}

__device__ __forceinline__ float epilogue64(const float (&a)[8],
                                            const float (&wv)[DIM], float bb) {
    float r0 = bb, r1 = 0.f, r2 = 0.f, r3 = 0.f;
    #pragma unroll
    for (int k = 0; k < DIM; k += 4) {
        r0 += __int_as_float(__builtin_amdgcn_readlane(
                  __float_as_int(a[(k + 0) & 7]), (k + 0) >> 3)) * wv[k + 0];
        r1 += __int_as_float(__builtin_amdgcn_readlane(
                  __float_as_int(a[(k + 1) & 7]), (k + 1) >> 3)) * wv[k + 1];
        r2 += __int_as_float(__builtin_amdgcn_readlane(
                  __float_as_int(a[(k + 2) & 7]), (k + 2) >> 3)) * wv[k + 2];
        r3 += __int_as_float(__builtin_amdgcn_readlane(
                  __float_as_int(a[(k + 3) & 7]), (k + 3) >> 3)) * wv[k + 3];
    }
    return (r0 + r1) + (r2 + r3);
}

// ---------------------------------------------------------------------------
// K4: block per 128-node bucket. LDS counting sort of its own segment, then
// branchless quad gather. (r11, measured 86.5us)
__global__ __launch_bounds__(256) void sort_gather_kernel(
        const unsigned short* __restrict__ xh, const int* __restrict__ binned,
        const int* __restrict__ gbase, int* __restrict__ gsrcs,
        const float* __restrict__ W, const float* __restrict__ bias,
        float* __restrict__ out, int N, int E) {
    __shared__ int cnt[BN];
    __shared__ int basel[BN + 1];
    __shared__ int tmp[BN];
    __shared__ int slds[CAP];

    const int t = threadIdx.x;
    const int g = blockIdx.x;
    const int lane = t & 63;
    const int wid = t >> 6;
    const int node0 = g << BN_SHIFT;

    float wv[DIM];
    #pragma unroll
    for (int k4 = 0; k4 < DIM / 4; ++k4) {
        float4 tw = *(const float4*)(W + (size_t)lane * DIM + k4 * 4);
        wv[k4 * 4 + 0] = tw.x; wv[k4 * 4 + 1] = tw.y;
        wv[k4 * 4 + 2] = tw.z; wv[k4 * 4 + 3] = tw.w;
    }
    const float bb = bias[lane];

    const int seg0 = gbase[g];
    const int seg1 = gbase[g + 1];
    const int total = seg1 - seg0;

    if (t < BN) cnt[t] = 0;
    __syncthreads();

    for (int i = seg0 + t; i < seg1; i += 256)
        atomicAdd(&cnt[binned[i] & BN_MASK], 1);
    __syncthreads();

    int myv = (t < BN) ? cnt[t] : 0;
    if (t < BN) tmp[t] = myv;
    __syncthreads();
    #pragma unroll
    for (int d = 1; d < BN; d <<= 1) {
        int u = (t < BN && t >= d) ? tmp[t - d] : 0;
        __syncthreads();
        if (t < BN) tmp[t] += u;
        __syncthreads();
    }
    if (t < BN) basel[t] = tmp[t] - myv;
    if (t == BN - 1) basel[BN] = tmp[t];
    if (t < BN) cnt[t] = tmp[t] - myv;        // cursors
    __syncthreads();

    const bool fits = (total <= CAP);
    if (fits) {
        for (int i = seg0 + t; i < seg1; i += 256) {
            int v = binned[i];                // L2-hot re-read (8KB window)
            int p = atomicAdd(&cnt[v & BN_MASK], 1);
            slds[p] = v >> BN_SHIFT;
        }
    } else {
        for (int i = seg0 + t; i < seg1; i += 256) {
            int v = binned[i];
            int p = atomicAdd(&cnt[v & BN_MASK], 1);
            gsrcs[seg0 + p] = v >> BN_SHIFT;
        }
    }
    __syncthreads();

    const int sub8 = lane >> 3;
    const int fb   = (lane & 7) << 3;
    const int zrow = N;
    const int slast = E + 48;
    for (int q = wid; q < (BN >> 2); q += 4) {
        const int nl = q << 2;
        int b0 = basel[nl + 0], e0 = basel[nl + 1];
        int b1 = basel[nl + 1], e1 = basel[nl + 2];
        int b2 = basel[nl + 2], e2 = basel[nl + 3];
        int b3 = basel[nl + 3], e3 = basel[nl + 4];
        int c0 = (e0 - b0 + 7) >> 3, c1 = (e1 - b1 + 7) >> 3;
        int c2 = (e2 - b2 + 7) >> 3, c3 = (e3 - b3 + 7) >> 3;
        int cmax = max(max(c0, c1), max(c2, c3));
        cmax = __builtin_amdgcn_readfirstlane(cmax);

        float A0[8] = {0.f,0.f,0.f,0.f,0.f,0.f,0.f,0.f};
        float A1[8] = {0.f,0.f,0.f,0.f,0.f,0.f,0.f,0.f};
        float A2[8] = {0.f,0.f,0.f,0.f,0.f,0.f,0.f,0.f};
        float A3[8] = {0.f,0.f,0.f,0.f,0.f,0.f,0.f,0.f};

        if (fits) {
            for (int c = 0; c < cmax; ++c) {
                const int o = (c << 3) + sub8;
                int i0 = b0 + o, i1 = b1 + o, i2 = b2 + o, i3 = b3 + o;
                int s0 = slds[min(i0, CAP - 1)];
                int s1 = slds[min(i1, CAP - 1)];
                int s2 = slds[min(i2, CAP - 1)];
                int s3 = slds[min(i3, CAP - 1)];
                s0 = (i0 < e0) ? s0 : zrow;
                s1 = (i1 < e1) ? s1 : zrow;
                s2 = (i2 < e2) ? s2 : zrow;
                s3 = (i3 < e3) ? s3 : zrow;
                uint4 v0 = *(const uint4*)(xh + (size_t)s0 * DIM + fb);
                uint4 v1 = *(const uint4*)(xh + (size_t)s1 * DIM + fb);
                uint4 v2 = *(const uint4*)(xh + (size_t)s2 * DIM + fb);
                uint4 v3 = *(const uint4*)(xh + (size_t)s3 * DIM + fb);
                acc8(A0, v0); acc8(A1, v1); acc8(A2, v2); acc8(A3, v3);
            }
        } else {
            for (int c = 0; c < cmax; ++c) {
                const int o = (c << 3) + sub8;
                int i0 = b0 + o, i1 = b1 + o, i2 = b2 + o, i3 = b3 + o;
                int s0 = gsrcs[min(seg0 + i0, slast)];
                int s1 = gsrcs[min(seg0 + i1, slast)];
                int s2 = gsrcs[min(seg0 + i2, slast)];
                int s3 = gsrcs[min(seg0 + i3, slast)];
                s0 = (i0 < e0) ? s0 : zrow;
                s1 = (i1 < e1) ? s1 : zrow;
                s2 = (i2 < e2) ? s2 : zrow;
                s3 = (i3 < e3) ? s3 : zrow;
                uint4 v0 = *(const uint4*)(xh + (size_t)s0 * DIM + fb);
                uint4 v1 = *(const uint4*)(xh + (size_t)s1 * DIM + fb);
                uint4 v2 = *(const uint4*)(xh + (size_t)s2 * DIM + fb);
                uint4 v3 = *(const uint4*)(xh + (size_t)s3 * DIM + fb);
                acc8(A0, v0); acc8(A1, v1); acc8(A2, v2); acc8(A3, v3);
            }
        }

        #pragma unroll
        for (int d = 8; d <= 32; d <<= 1) {
            #pragma unroll
            for (int j = 0; j < 8; ++j) {
                A0[j] += __shfl_xor(A0[j], d, 64);
                A1[j] += __shfl_xor(A1[j], d, 64);
                A2[j] += __shfl_xor(A2[j], d, 64);
                A3[j] += __shfl_xor(A3[j], d, 64);
            }
        }

        const int n0 = node0 + nl;
        if (n0 + 0 < N) out[(size_t)(n0 + 0) * DIM + lane] = epilogue64(A0, wv, bb);
        if (n0 + 1 < N) out[(size_t)(n0 + 1) * DIM + lane] = epilogue64(A1, wv, bb);
        if (n0 + 2 < N) out[(size_t)(n0 + 2) * DIM + lane] = epilogue64(A2, wv, bb);
        if (n0 + 3 < N) out[(size_t)(n0 + 3) * DIM + lane] = epilogue64(A3, wv, bb);
    }
}

// ------------------- tier D: atomic scatter fallback -----------------------
__global__ void gcn_scatter_kernel(const float* __restrict__ x,
                                   const int* __restrict__ edge_index,
                                   float* __restrict__ out, int n_edges) {
    int gid = blockIdx.x * blockDim.x + threadIdx.x;
    int e = gid >> 4;
    if (e >= n_edges) return;
    int j = (gid & 15) << 2;
    int src = edge_index[e];
    int dst = edge_index[n_edges + e];
    const float4 v = *(const float4*)(x + (size_t)src * DIM + j);
    float* o = out + (size_t)dst * DIM + j;
    atomicAdd(o + 0, v.x); atomicAdd(o + 1, v.y);
    atomicAdd(o + 2, v.z); atomicAdd(o + 3, v.w);
}

__global__ void gcn_linear_inplace_kernel(float* __restrict__ out,
                                          const float* __restrict__ W,
                                          const float* __restrict__ bias,
                                          int n_nodes) {
    __shared__ float Wt[DIM * DIM];
    __shared__ float rows[4][DIM];
    int tid = threadIdx.x;
    int col = tid & 63;
    int r = tid >> 6;
    for (int i = tid; i < DIM * DIM; i += 256) {
        int c = i >> 6, k = i & 63;
        Wt[k * DIM + c] = W[i];
    }
    int row = blockIdx.x * 4 + r;
    if (row < n_nodes) rows[r][col] = out[(size_t)row * DIM + col];
    __syncthreads();
    if (row < n_nodes) {
        float a = 0.f;
        #pragma unroll
        for (int k = 0; k < DIM; ++k) a += rows[r][k] * Wt[k * DIM + col];
        out[(size_t)row * DIM + col] = a + bias[col];
    }
}

// ===========================================================================
extern "C" void kernel_launch(void* const* d_in, const int* in_sizes, int n_in,
                              void* d_out, int out_size, void* d_ws, size_t ws_size,
                              hipStream_t stream) {
    const float* x          = (const float*)d_in[0];   // [N, 64]
    const float* W          = (const float*)d_in[1];   // [64, 64]
    const float* bias       = (const float*)d_in[2];   // [64]
    const int*   edge_index = (const int*)d_in[3];     // [2, E] (int32)

    const int E = in_sizes[3] / 2;
    const int N = in_sizes[0] / DIM;
    float* out = (float*)d_out;

    const int nb = (N + BN - 1) >> BN_SHIFT;

    auto align256 = [](size_t v) { return (v + 255) & ~(size_t)255; };
    const size_t xb_b   = align256(((size_t)N + 1) * DIM * 2);   // +1 zero row
    const size_t bin_b  = align256((size_t)E * 4);
    const size_t scan_b = align256((size_t)nb * PB * 4);
    const size_t rt_b   = align256((size_t)nb * 4);
    const size_t gb_b   = align256(((size_t)nb + 1) * 4);
    const size_t srcs_b = align256(((size_t)E + 64) * 4);        // overflow path
    const size_t needA = xb_b + bin_b + scan_b + rt_b + gb_b + srcs_b;

    // src must fit in 25 bits for the (src<<7)|dstlo packing
    if (nb <= NB_MAX && N < (1 << 24) && ws_size >= needA) {
        char* p = (char*)d_ws;
        ushort4* xb4 = (ushort4*)p;          p += xb_b;
        int* binned  = (int*)p;              p += bin_b;
        int* scanbuf = (int*)p;              p += scan_b;
        int* rowtot  = (int*)p;              p += rt_b;
        int* gbase   = (int*)p;              p += gb_b;
        int* gsrcs   = (int*)p;

        const int total4 = N * DIM / 4;

        convert_hist_kernel<<<PB, 1024, 0, stream>>>(
            x, edge_index, xb4, scanbuf, E, N, nb, total4);
        rowscan_kernel<<<(nb + 3) / 4, 256, 0, stream>>>(scanbuf, rowtot, nb);
        basescan_kernel<<<1, 256, 0, stream>>>(rowtot, gbase, nb, E);
        scatter_kernel<<<PB, 1024, 0, stream>>>(
            edge_index, scanbuf, gbase, binned, E, nb);
        sort_gather_kernel<<<nb, 256, 0, stream>>>(
            (const unsigned short*)xb4, binned, gbase, gsrcs, W, bias, out, N, E);
    } else {
        hipMemsetAsync(d_out, 0, (size_t)out_size * sizeof(float), stream);
        long long total = (long long)E * 16;
        int grid = (int)((total + 255) / 256);
        gcn_scatter_kernel<<<grid, 256, 0, stream>>>(x, edge_index, out, E);
        int lgrid = (N + 3) / 4;
        gcn_linear_inplace_kernel<<<lgrid, 256, 0, stream>>>(out, W, bias, N);
    }
}